// Round 1
// baseline (201.069 us; speedup 1.0000x reference)
//
#include <hip/hip_runtime.h>

#define NN 4
#define CC 20
#define HH 64
#define WW 2048
#define CG 4           // channel groups
#define CPG (CC / CG)  // 5 channels per group
#define PX 4           // pixels per thread
#define HB 2           // output rows per block

// HB=2: one block computes two output rows (h0, h0+1); the 6 tap rows
// h0-2..h0+3 are loaded ONCE and shared by both outputs (-40% loads).
// 1-D grid with XCD z-affinity swizzle: id%8 -> z-slice, phased (z, z+8),
// so each XCD's L2 sees one ~4.7MB (n,cg) slice with h-streaming order
// and dy row re-reads become L2 hits.
__global__ __launch_bounds__(256, 3) void lc_xyz_kernel(
    const float* __restrict__ xyz,
    const float* __restrict__ softmax,
    const int* __restrict__ mask,
    float* __restrict__ out)
{
    const unsigned id = blockIdx.x;                 // 0..1023
    const int z  = (int)(id & 7u) + (int)((id >> 9) << 3);  // 0..15, XCD-affine
    const int jj = (int)((id >> 3) & 63u);          // 0..63
    const int hp = jj >> 1;                         // 0..31  (h-pair, streams within XCD)
    const int xb = jj & 1;                          // 0..1   (x half of the row)
    const int n  = z >> 2;
    const int cg = z & 3;
    const int h0 = hp * HB;
    const int t  = xb * 256 + (int)threadIdx.x;     // pixel-quad index in row: 0..511
    const int p0 = t * PX;
    const int hw = HH * WW;

    const float* xbse = xyz     + (size_t)n * 3  * hw;
    const float* smb  = softmax + (size_t)n * CC * hw + (size_t)(cg * CPG) * hw;
    const int*   mb   = mask    + (size_t)n * hw;

    // Centers for both output rows.
    const int ctr0 = h0 * WW + p0;
    const float4 cxv0 = *(const float4*)(xbse + 0 * hw + ctr0);
    const float4 cyv0 = *(const float4*)(xbse + 1 * hw + ctr0);
    const float4 czv0 = *(const float4*)(xbse + 2 * hw + ctr0);
    const float4 cxv1 = *(const float4*)(xbse + 0 * hw + ctr0 + WW);
    const float4 cyv1 = *(const float4*)(xbse + 1 * hw + ctr0 + WW);
    const float4 czv1 = *(const float4*)(xbse + 2 * hw + ctr0 + WW);
    const float cx[2][PX] = {{cxv0.x, cxv0.y, cxv0.z, cxv0.w}, {cxv1.x, cxv1.y, cxv1.z, cxv1.w}};
    const float cy[2][PX] = {{cyv0.x, cyv0.y, cyv0.z, cyv0.w}, {cyv1.x, cyv1.y, cyv1.z, cyv1.w}};
    const float cz[2][PX] = {{czv0.x, czv0.y, czv0.z, czv0.w}, {czv1.x, czv1.y, czv1.z, czv1.w}};

    float acc0[CPG][PX], acc1[CPG][PX];
#pragma unroll
    for (int c = 0; c < CPG; ++c)
#pragma unroll
        for (int i = 0; i < PX; ++i) { acc0[c][i] = 0.f; acc1[c][i] = 0.f; }

    // Window indices j=0..11 map to w = p0-4+j; taps use j = i+dx+2 in [2,9].
    // Aligned 16B chunks at p0-4, p0, p0+4; edge chunks clamped (their taps
    // are zeroed via validity; all VALID taps come from unclamped chunks).
    int c0 = p0 - 4; if (c0 < 0) c0 = 0;
    const int c1 = p0;
    int c2 = p0 + 4; if (c2 > WW - 4) c2 = WW - 4;

    float vf[12];
#pragma unroll
    for (int q = 2; q <= 9; ++q)
        vf[q] = ((unsigned)(p0 - 4 + q) < (unsigned)WW) ? 1.f : 0.f;

    // Tap rows for outputs h0 and h0+1: dr in [-2, 3].
#pragma unroll
    for (int dr = -2; dr <= 3; ++dr) {
        const int row = h0 + dr;
        if ((unsigned)row >= (unsigned)HH) continue;   // wave-uniform
        const int rb = row * WW;

        // Batched independent row loads: 3 int4 + 9 float4.
        const int4 m0 = *(const int4*)(mb + rb + c0);
        const int4 m1 = *(const int4*)(mb + rb + c1);
        const int4 m2 = *(const int4*)(mb + rb + c2);
        const float4 x0 = *(const float4*)(xbse + 0 * hw + rb + c0);
        const float4 x1 = *(const float4*)(xbse + 0 * hw + rb + c1);
        const float4 x2 = *(const float4*)(xbse + 0 * hw + rb + c2);
        const float4 y0 = *(const float4*)(xbse + 1 * hw + rb + c0);
        const float4 y1 = *(const float4*)(xbse + 1 * hw + rb + c1);
        const float4 y2 = *(const float4*)(xbse + 1 * hw + rb + c2);
        const float4 z0 = *(const float4*)(xbse + 2 * hw + rb + c0);
        const float4 z1 = *(const float4*)(xbse + 2 * hw + rb + c1);
        const float4 z2 = *(const float4*)(xbse + 2 * hw + rb + c2);

        const float xw[12] = {x0.x,x0.y,x0.z,x0.w, x1.x,x1.y,x1.z,x1.w, x2.x,x2.y,x2.z,x2.w};
        const float yw[12] = {y0.x,y0.y,y0.z,y0.w, y1.x,y1.y,y1.z,y1.w, y2.x,y2.y,y2.z,y2.w};
        const float zw[12] = {z0.x,z0.y,z0.z,z0.w, z1.x,z1.y,z1.z,z1.w, z2.x,z2.y,z2.z,z2.w};
        const int   mi[12] = {m0.x,m0.y,m0.z,m0.w, m1.x,m1.y,m1.z,m1.w, m2.x,m2.y,m2.z,m2.w};

        float mf[12];
#pragma unroll
        for (int q = 2; q <= 9; ++q) mf[q] = vf[q] * (float)mi[q];

        // Compile-time (after unroll) activity of each output row.
        const bool act0 = (dr <= 2);    // |dr| <= 2 for row h0
        const bool act1 = (dr >= -1);   // dr-1 in [-2,2] for row h0+1

        // Gaussian weights per (output row, pixel, tap); shared across channels.
        float g0[PX][5], g1[PX][5];
        if (act0) {
#pragma unroll
            for (int i = 0; i < PX; ++i)
#pragma unroll
                for (int dx = 0; dx < 5; ++dx) {
                    const int q = i + dx + 2;
                    const float ax = xw[q] - cx[0][i];
                    const float ay = yw[q] - cy[0][i];
                    const float az = zw[q] - cz[0][i];
                    const float d2 = ax * ax + ay * ay + az * az;
                    g0[i][dx] = mf[q] * __expf(-0.5f * d2);
                }
        }
        if (act1) {
#pragma unroll
            for (int i = 0; i < PX; ++i)
#pragma unroll
                for (int dx = 0; dx < 5; ++dx) {
                    const int q = i + dx + 2;
                    const float ax = xw[q] - cx[1][i];
                    const float ay = yw[q] - cy[1][i];
                    const float az = zw[q] - cz[1][i];
                    const float d2 = ax * ax + ay * ay + az * az;
                    g1[i][dx] = mf[q] * __expf(-0.5f * d2);
                }
        }

        // Channel loop: 3 float4 loads feed BOTH output rows (the HB=2 win).
#pragma unroll
        for (int c = 0; c < CPG; ++c) {
            const float* sp = smb + (size_t)c * hw + rb;
            const float4 s0 = *(const float4*)(sp + c0);
            const float4 s1 = *(const float4*)(sp + c1);
            const float4 s2 = *(const float4*)(sp + c2);
            const float sw[12] = {s0.x,s0.y,s0.z,s0.w, s1.x,s1.y,s1.z,s1.w, s2.x,s2.y,s2.z,s2.w};
            if (act0) {
#pragma unroll
                for (int i = 0; i < PX; ++i) {
                    float a = acc0[c][i];
#pragma unroll
                    for (int dx = 0; dx < 5; ++dx)
                        a = fmaf(g0[i][dx], sw[i + dx + 2], a);
                    acc0[c][i] = a;
                }
            }
            if (act1) {
#pragma unroll
                for (int i = 0; i < PX; ++i) {
                    float a = acc1[c][i];
#pragma unroll
                    for (int dx = 0; dx < 5; ++dx)
                        a = fmaf(g1[i][dx], sw[i + dx + 2], a);
                    acc1[c][i] = a;
                }
            }
        }
    }

    float* ob = out + (size_t)n * CC * hw + (size_t)(cg * CPG) * hw + ctr0;
#pragma unroll
    for (int c = 0; c < CPG; ++c) {
        *(float4*)(ob + (size_t)c * hw) =
            make_float4(acc0[c][0], acc0[c][1], acc0[c][2], acc0[c][3]);
        *(float4*)(ob + (size_t)c * hw + WW) =
            make_float4(acc1[c][0], acc1[c][1], acc1[c][2], acc1[c][3]);
    }
}

extern "C" void kernel_launch(void* const* d_in, const int* in_sizes, int n_in,
                              void* d_out, int out_size, void* d_ws, size_t ws_size,
                              hipStream_t stream) {
    const float* xyz     = (const float*)d_in[0];
    const float* softmax = (const float*)d_in[1];
    const int*   mask    = (const int*)d_in[2];
    float*       out     = (float*)d_out;

    dim3 block(256, 1, 1);
    dim3 grid((WW / (PX * 256)) * (HH / HB) * (NN * CG), 1, 1);  // 1024 blocks, swizzled decode
    hipLaunchKernelGGL(lc_xyz_kernel, grid, block, 0, stream,
                       xyz, softmax, mask, out);
}

// Round 2
// 143.071 us; speedup vs baseline: 1.4054x; 1.4054x over previous
//
#include <hip/hip_runtime.h>

#define NN 4
#define CC 20
#define HH 64
#define WW 2048
#define CG 4           // channel groups
#define CPG (CC / CG)  // 5 channels per group
#define PX 4           // pixels per thread

// Round-0 proven body (VGPR=64, no spills) + XCD-affinity block swizzle.
// HW assigns block id round-robin to XCDs (id%8). We decode a virtual
// linear index v = xcd*256 + (id>>3) so each XCD owns 2 consecutive
// z-slices (same n -> xyz/mask shared): per-XCD working set ~7.3MB
// instead of ~50MB, so dy-row reuse and window-chunk overlap hit L2.
__global__ __launch_bounds__(256, 4) void lc_xyz_kernel(
    const float* __restrict__ xyz,
    const float* __restrict__ softmax,
    const int* __restrict__ mask,
    float* __restrict__ out)
{
    const unsigned id  = blockIdx.x;            // 0..2047
    const unsigned xcd = id & 7u;               // round-robin XCD slot
    const unsigned v   = xcd * 256u + (id >> 3); // contiguous chunk per XCD
    // v = x + 2*h + 128*z  (z-major: each XCD gets z in {2*xcd, 2*xcd+1})
    const int xhalf = (int)(v & 1u);
    const int h     = (int)((v >> 1) & 63u);
    const int z     = (int)(v >> 7);            // 0..15
    const int n     = z >> 2;
    const int cg    = z & 3;

    const int t  = xhalf * 256 + (int)threadIdx.x;  // pixel-quad index in row: 0..511
    const int hw = HH * WW;
    const int p0 = t * PX;

    const float* xb  = xyz     + (size_t)n * 3  * hw;
    const float* smb = softmax + (size_t)n * CC * hw + (size_t)(cg * CPG) * hw;
    const int*   mb  = mask    + (size_t)n * hw;

    const int ctr = h * WW + p0;
    const float4 cxv = *(const float4*)(xb + 0 * hw + ctr);
    const float4 cyv = *(const float4*)(xb + 1 * hw + ctr);
    const float4 czv = *(const float4*)(xb + 2 * hw + ctr);
    const float cx[PX] = {cxv.x, cxv.y, cxv.z, cxv.w};
    const float cy[PX] = {cyv.x, cyv.y, cyv.z, cyv.w};
    const float cz[PX] = {czv.x, czv.y, czv.z, czv.w};

    float acc[CPG][PX];
#pragma unroll
    for (int c = 0; c < CPG; ++c)
#pragma unroll
        for (int i = 0; i < PX; ++i) acc[c][i] = 0.f;

    // Window indices j=0..11 map to w = p0-4+j; taps use j = i+dx+2 in [2,9].
    // Aligned 16B chunks at p0-4, p0, p0+4; edge chunks clamped (their taps
    // are zeroed via validity, and all VALID taps come from unclamped chunks).
    int c0 = p0 - 4; if (c0 < 0) c0 = 0;
    const int c1 = p0;
    int c2 = p0 + 4; if (c2 > WW - 4) c2 = WW - 4;

    float vf[12];
#pragma unroll
    for (int j = 2; j <= 9; ++j)
        vf[j] = ((unsigned)(p0 - 4 + j) < (unsigned)WW) ? 1.f : 0.f;

#pragma unroll
    for (int dy = -2; dy <= 2; ++dy) {
        const int row = h + dy;
        if ((unsigned)row >= (unsigned)HH) continue;   // wave-uniform
        const int rb = row * WW;

        // Batched independent row loads: 3 int4 + 9 float4.
        const int4 m0 = *(const int4*)(mb + rb + c0);
        const int4 m1 = *(const int4*)(mb + rb + c1);
        const int4 m2 = *(const int4*)(mb + rb + c2);
        const float4 x0 = *(const float4*)(xb + 0 * hw + rb + c0);
        const float4 x1 = *(const float4*)(xb + 0 * hw + rb + c1);
        const float4 x2 = *(const float4*)(xb + 0 * hw + rb + c2);
        const float4 y0 = *(const float4*)(xb + 1 * hw + rb + c0);
        const float4 y1 = *(const float4*)(xb + 1 * hw + rb + c1);
        const float4 y2 = *(const float4*)(xb + 1 * hw + rb + c2);
        const float4 z0 = *(const float4*)(xb + 2 * hw + rb + c0);
        const float4 z1 = *(const float4*)(xb + 2 * hw + rb + c1);
        const float4 z2 = *(const float4*)(xb + 2 * hw + rb + c2);

        const float xw[12] = {x0.x,x0.y,x0.z,x0.w, x1.x,x1.y,x1.z,x1.w, x2.x,x2.y,x2.z,x2.w};
        const float yw[12] = {y0.x,y0.y,y0.z,y0.w, y1.x,y1.y,y1.z,y1.w, y2.x,y2.y,y2.z,y2.w};
        const float zw[12] = {z0.x,z0.y,z0.z,z0.w, z1.x,z1.y,z1.z,z1.w, z2.x,z2.y,z2.z,z2.w};
        const int   mi[12] = {m0.x,m0.y,m0.z,m0.w, m1.x,m1.y,m1.z,m1.w, m2.x,m2.y,m2.z,m2.w};

        float mf[12];
#pragma unroll
        for (int j = 2; j <= 9; ++j) mf[j] = vf[j] * (float)mi[j];

        // Gaussian weights, once per (pixel, tap), shared across channels.
        float g[PX][5];
#pragma unroll
        for (int i = 0; i < PX; ++i) {
#pragma unroll
            for (int dx = 0; dx < 5; ++dx) {
                const int j = i + dx + 2;
                const float ax = xw[j] - cx[i];
                const float ay = yw[j] - cy[i];
                const float az = zw[j] - cz[i];
                const float d2 = ax * ax + ay * ay + az * az;
                g[i][dx] = mf[j] * __expf(-0.5f * d2);
            }
        }

        // Channel loop: 3 float4 loads + 20 FMA per channel.
#pragma unroll
        for (int c = 0; c < CPG; ++c) {
            const float* sp = smb + (size_t)c * hw + rb;
            const float4 s0 = *(const float4*)(sp + c0);
            const float4 s1 = *(const float4*)(sp + c1);
            const float4 s2 = *(const float4*)(sp + c2);
            const float sw[12] = {s0.x,s0.y,s0.z,s0.w, s1.x,s1.y,s1.z,s1.w, s2.x,s2.y,s2.z,s2.w};
#pragma unroll
            for (int i = 0; i < PX; ++i) {
                float a = acc[c][i];
#pragma unroll
                for (int dx = 0; dx < 5; ++dx)
                    a = fmaf(g[i][dx], sw[i + dx + 2], a);
                acc[c][i] = a;
            }
        }
    }

    float* ob = out + (size_t)n * CC * hw + (size_t)(cg * CPG) * hw + ctr;
#pragma unroll
    for (int c = 0; c < CPG; ++c)
        *(float4*)(ob + (size_t)c * hw) =
            make_float4(acc[c][0], acc[c][1], acc[c][2], acc[c][3]);
}

extern "C" void kernel_launch(void* const* d_in, const int* in_sizes, int n_in,
                              void* d_out, int out_size, void* d_ws, size_t ws_size,
                              hipStream_t stream) {
    const float* xyz     = (const float*)d_in[0];
    const float* softmax = (const float*)d_in[1];
    const int*   mask    = (const int*)d_in[2];
    float*       out     = (float*)d_out;

    dim3 block(256, 1, 1);
    dim3 grid((WW / (PX * 256)) * HH * (NN * CG), 1, 1);  // 2048 blocks, 1-D swizzled
    hipLaunchKernelGGL(lc_xyz_kernel, grid, block, 0, stream,
                       xyz, softmax, mask, out);
}